// Round 1
// baseline (581.755 us; speedup 1.0000x reference)
//
#include <hip/hip_runtime.h>

typedef __attribute__((ext_vector_type(8))) __bf16 bf16x8;
typedef __attribute__((ext_vector_type(4))) float f32x4;

#define NB 131072   // batch
#define BT 64       // batch rows per block

__device__ __forceinline__ unsigned short f2bf(float f) {
  // round-to-nearest-even f32 -> bf16 (inputs are finite; no NaN handling needed)
  unsigned int u = __builtin_bit_cast(unsigned int, f);
  u += 0x7fffu + ((u >> 16) & 1u);
  return (unsigned short)(u >> 16);
}

// XOR-swizzled LDS addressing (T2): spreads row-strided ds_read_b128 across banks.
#define INP_ADDR(r, byte) (((r) << 8) + ((byte) ^ (((r) & 7) << 4)))   // inp: 256 B/row
#define X_ADDR(r, byte)   (((r) << 9) + ((byte) ^ (((r) & 7) << 4)))   // x1/x2: 512 B/row

// ---------------- prep: bf16 frag-ordered weights + per-pair fused bias ----------------
// ws layout (bytes):
//   W1f @ 0      : 32768 bf16  (kf<4,  nf<16)  from W1[128][256]
//   W2f @ 65536  : 65536 bf16  (kf<8,  nf<16)  from W2[256][256]
//   Whf @ 196608 : 32768 bf16  (kf<8,  nf<8)   from [Wm|Wv] (256 x 128)
//   b1p @ 262144 : 768 f32     b1 + one-hot-folded W1 rows, per pair
__global__ void prep_kernel(const float* __restrict__ W1, const float* __restrict__ b1,
                            const float* __restrict__ W2,
                            const float* __restrict__ Wm, const float* __restrict__ Wv,
                            unsigned short* __restrict__ W1f, unsigned short* __restrict__ W2f,
                            unsigned short* __restrict__ Whf, float* __restrict__ b1p) {
  int tid = blockIdx.x * 256 + threadIdx.x;
  int NT = gridDim.x * 256;
  for (int i = tid; i < 32768; i += NT) {   // W1f
    int j = i & 7, lane = (i >> 3) & 63, f = i >> 9;
    int nf = f & 15, kf = f >> 4;
    int n = nf * 16 + (lane & 15);
    int k = kf * 32 + 8 * (lane >> 4) + j;
    W1f[i] = f2bf(W1[k * 256 + n]);
  }
  for (int i = tid; i < 65536; i += NT) {   // W2f
    int j = i & 7, lane = (i >> 3) & 63, f = i >> 9;
    int nf = f & 15, kf = f >> 4;
    int n = nf * 16 + (lane & 15);
    int k = kf * 32 + 8 * (lane >> 4) + j;
    W2f[i] = f2bf(W2[k * 256 + n]);
  }
  for (int i = tid; i < 32768; i += NT) {   // Whf = [Wm | Wv]
    int j = i & 7, lane = (i >> 3) & 63, f = i >> 9;
    int nf = f & 7, kf = f >> 3;
    int n = nf * 16 + (lane & 15);
    int k = kf * 32 + 8 * (lane >> 4) + j;
    Whf[i] = f2bf(n < 64 ? Wm[k * 64 + n] : Wv[k * 64 + (n - 64)]);
  }
  if (tid < 768) {                          // b1p: pairs (0,1),(0,2),(1,2) -> W1 rows {0,4},{0,5},{1,5}
    int p = tid >> 8, h = tid & 255;
    const int r1[3] = {0, 0, 1};
    const int r2[3] = {4, 5, 5};
    b1p[tid] = b1[h] + W1[r1[p] * 256 + h] + W1[r2[p] * 256 + h];
  }
}

// ---------------- fused encoder ----------------
__global__ __launch_bounds__(256, 2) void fused_kernel(
    const float* __restrict__ init_s, const float* __restrict__ cur_s,
    const float* __restrict__ emb,
    const unsigned short* __restrict__ W1f, const unsigned short* __restrict__ W2f,
    const unsigned short* __restrict__ Whf,
    const float* __restrict__ b1p, const float* __restrict__ b2,
    const float* __restrict__ bm, const float* __restrict__ bv,
    float* __restrict__ out) {
  extern __shared__ char smem[];
  char* inp = smem;                        // [64][128] bf16, swizzled (16 KB)
  char* x1  = smem + 16384;                // [64][256] bf16, swizzled (32 KB)
  char* x2  = smem + 49152;                // [64][256] bf16, swizzled (32 KB)
  float* ostage = (float*)(smem + 16384);  // [64][128] f32, aliases x1 (dead by heads)

  const int t = threadIdx.x;
  const int lane = t & 63;
  const int wave = t >> 6;
  const int ql = lane & 15, qw = lane >> 4;
  const int b0 = blockIdx.x * BT;

  // zero one-hot-folded cols 0..5 (once)
  if (t < 64) {
    *(unsigned long long*)(inp + INP_ADDR(t, 0)) = 0ull;  // bytes 0-7
    *(unsigned int*)(inp + INP_ADDR(t, 8)) = 0u;          // bytes 8-11
  }
  // embedding cols 12..127 (once): 64 rows x 29 float4
  for (int i = t; i < 64 * 29; i += 256) {
    int r = i / 29;
    int c4 = i - r * 29;
    const float4 v = *(const float4*)(emb + (size_t)(b0 + r) * 116 + c4 * 4);
    unsigned long long pk = (unsigned long long)f2bf(v.x)
                          | ((unsigned long long)f2bf(v.y) << 16)
                          | ((unsigned long long)f2bf(v.z) << 32)
                          | ((unsigned long long)f2bf(v.w) << 48);
    *(unsigned long long*)(inp + INP_ADDR(r, 24 + 8 * c4)) = pk;
  }

  const int IDSa[3] = {0, 1, 2};
  const int IDSb[3] = {3, 5, 7};
  const int IDSc[3] = {4, 6, 8};

#pragma unroll 1
  for (int p = 0; p < 3; ++p) {
    // s-feature cols 6..11 for this pair
    if (t < 64) {
      const float* isr = init_s + (size_t)(b0 + t) * 9;
      const float* csr = cur_s + (size_t)(b0 + t) * 9;
      float a0 = isr[IDSa[p]], a1 = isr[IDSb[p]], a2 = isr[IDSc[p]];
      float c0 = csr[IDSa[p]], c1 = csr[IDSb[p]], c2 = csr[IDSc[p]];
      *(unsigned int*)(inp + INP_ADDR(t, 12)) = (unsigned)f2bf(a0) | ((unsigned)f2bf(a1) << 16);
      *(unsigned int*)(inp + INP_ADDR(t, 16)) = (unsigned)f2bf(a2) | ((unsigned)f2bf(c0) << 16);
      *(unsigned int*)(inp + INP_ADDR(t, 20)) = (unsigned)f2bf(c1) | ((unsigned)f2bf(c2) << 16);
    }
    __syncthreads();

    // ---- layer 1: [64x128] @ [128x256], wave owns 64 cols ----
    {
      f32x4 acc[4][4];
#pragma unroll
      for (int ni = 0; ni < 4; ++ni) {
        float bvv = b1p[p * 256 + wave * 64 + ni * 16 + ql];
#pragma unroll
        for (int mi = 0; mi < 4; ++mi) acc[mi][ni] = (f32x4){bvv, bvv, bvv, bvv};
      }
#pragma unroll
      for (int kf = 0; kf < 4; ++kf) {
        bf16x8 a[4];
#pragma unroll
        for (int mi = 0; mi < 4; ++mi)
          a[mi] = *(const bf16x8*)(inp + INP_ADDR(mi * 16 + ql, kf * 64 + qw * 16));
#pragma unroll
        for (int ni = 0; ni < 4; ++ni) {
          bf16x8 w = *(const bf16x8*)(W1f + (size_t)((kf * 16 + wave * 4 + ni) * 64 + lane) * 8);
#pragma unroll
          for (int mi = 0; mi < 4; ++mi)
            acc[mi][ni] = __builtin_amdgcn_mfma_f32_16x16x32_bf16(a[mi], w, acc[mi][ni], 0, 0, 0);
        }
      }
#pragma unroll
      for (int mi = 0; mi < 4; ++mi)
#pragma unroll
        for (int ni = 0; ni < 4; ++ni) {
          int col = wave * 64 + ni * 16 + ql;
#pragma unroll
          for (int r = 0; r < 4; ++r) {
            int row = mi * 16 + qw * 4 + r;
            float v = acc[mi][ni][r];
            v = v > 0.f ? v : 0.f;
            *(unsigned short*)(x1 + X_ADDR(row, col * 2)) = f2bf(v);
          }
        }
    }
    __syncthreads();

    // ---- layer 2: [64x256] @ [256x256] ----
    {
      f32x4 acc[4][4];
#pragma unroll
      for (int ni = 0; ni < 4; ++ni) {
        float bvv = b2[wave * 64 + ni * 16 + ql];
#pragma unroll
        for (int mi = 0; mi < 4; ++mi) acc[mi][ni] = (f32x4){bvv, bvv, bvv, bvv};
      }
#pragma unroll
      for (int kf = 0; kf < 8; ++kf) {
        bf16x8 a[4];
#pragma unroll
        for (int mi = 0; mi < 4; ++mi)
          a[mi] = *(const bf16x8*)(x1 + X_ADDR(mi * 16 + ql, kf * 64 + qw * 16));
#pragma unroll
        for (int ni = 0; ni < 4; ++ni) {
          bf16x8 w = *(const bf16x8*)(W2f + (size_t)((kf * 16 + wave * 4 + ni) * 64 + lane) * 8);
#pragma unroll
          for (int mi = 0; mi < 4; ++mi)
            acc[mi][ni] = __builtin_amdgcn_mfma_f32_16x16x32_bf16(a[mi], w, acc[mi][ni], 0, 0, 0);
        }
      }
#pragma unroll
      for (int mi = 0; mi < 4; ++mi)
#pragma unroll
        for (int ni = 0; ni < 4; ++ni) {
          int col = wave * 64 + ni * 16 + ql;
#pragma unroll
          for (int r = 0; r < 4; ++r) {
            int row = mi * 16 + qw * 4 + r;
            float v = acc[mi][ni][r];
            v = v > 0.f ? v : 0.f;
            *(unsigned short*)(x2 + X_ADDR(row, col * 2)) = f2bf(v);
          }
        }
    }
    __syncthreads();

    // ---- heads: [64x256] @ [256x128] ([Wm|Wv]), wave owns 32 cols ----
    {
      f32x4 hacc[4][2];
#pragma unroll
      for (int ni = 0; ni < 2; ++ni) {
        int col = wave * 32 + ni * 16 + ql;
        float hb = (col < 64) ? bm[col] : bv[col - 64];
#pragma unroll
        for (int mi = 0; mi < 4; ++mi) hacc[mi][ni] = (f32x4){hb, hb, hb, hb};
      }
#pragma unroll
      for (int kf = 0; kf < 8; ++kf) {
        bf16x8 a[4];
#pragma unroll
        for (int mi = 0; mi < 4; ++mi)
          a[mi] = *(const bf16x8*)(x2 + X_ADDR(mi * 16 + ql, kf * 64 + qw * 16));
#pragma unroll
        for (int ni = 0; ni < 2; ++ni) {
          bf16x8 w = *(const bf16x8*)(Whf + (size_t)((kf * 8 + wave * 2 + ni) * 64 + lane) * 8);
#pragma unroll
          for (int mi = 0; mi < 4; ++mi)
            hacc[mi][ni] = __builtin_amdgcn_mfma_f32_16x16x32_bf16(a[mi], w, hacc[mi][ni], 0, 0, 0);
        }
      }
#pragma unroll
      for (int mi = 0; mi < 4; ++mi)
#pragma unroll
        for (int ni = 0; ni < 2; ++ni) {
          int col = wave * 32 + ni * 16 + ql;
#pragma unroll
          for (int r = 0; r < 4; ++r)
            ostage[(mi * 16 + qw * 4 + r) * 128 + col] = hacc[mi][ni][r];
        }
    }
    __syncthreads();

    // ---- coalesced output: cols 0-63 -> means, 64-127 -> log_vars ----
    for (int i = t; i < 64 * 32; i += 256) {
      int r = i >> 5, c4 = i & 31;
      float4 v = *(const float4*)(ostage + r * 128 + c4 * 4);
      size_t off;
      if (c4 < 16)
        off = ((size_t)p * NB + b0 + r) * 64 + (size_t)c4 * 4;
      else
        off = (size_t)3 * NB * 64 + ((size_t)p * NB + b0 + r) * 64 + (size_t)(c4 - 16) * 4;
      *(float4*)(out + off) = v;
    }
    __syncthreads();
  }
}

extern "C" void kernel_launch(void* const* d_in, const int* in_sizes, int n_in,
                              void* d_out, int out_size, void* d_ws, size_t ws_size,
                              hipStream_t stream) {
  (void)in_sizes; (void)n_in; (void)out_size; (void)ws_size;
  const float* init_s = (const float*)d_in[0];
  const float* cur_s  = (const float*)d_in[1];
  const float* emb    = (const float*)d_in[2];
  const float* W1 = (const float*)d_in[3];
  const float* b1 = (const float*)d_in[4];
  const float* W2 = (const float*)d_in[5];
  const float* b2 = (const float*)d_in[6];
  const float* Wm = (const float*)d_in[7];
  const float* bm = (const float*)d_in[8];
  const float* Wv = (const float*)d_in[9];
  const float* bv = (const float*)d_in[10];

  unsigned short* W1f = (unsigned short*)d_ws;
  unsigned short* W2f = (unsigned short*)((char*)d_ws + 65536);
  unsigned short* Whf = (unsigned short*)((char*)d_ws + 196608);
  float* b1p = (float*)((char*)d_ws + 262144);

  prep_kernel<<<128, 256, 0, stream>>>(W1, b1, W2, Wm, Wv, W1f, W2f, Whf, b1p);

  (void)hipFuncSetAttribute((const void*)fused_kernel,
                            hipFuncAttributeMaxDynamicSharedMemorySize, 81920);
  fused_kernel<<<NB / BT, 256, 81920, stream>>>(init_s, cur_s, emb, W1f, W2f, Whf,
                                                b1p, b2, bm, bv, (float*)d_out);
}

// Round 2
// 338.692 us; speedup vs baseline: 1.7177x; 1.7177x over previous
//
#include <hip/hip_runtime.h>

typedef __attribute__((ext_vector_type(8))) __bf16 bf16x8;
typedef __attribute__((ext_vector_type(4))) float f32x4;
typedef unsigned int u32;
typedef unsigned short u16;

#define NB 131072   // batch
#define NT1 2048    // tiles of 64 rows per pair
#define NTT 6144    // total tiles (3 pairs)

__device__ __forceinline__ u16 f2bf(float f) {
  unsigned int u = __builtin_bit_cast(unsigned int, f);
  u += 0x7fffu + ((u >> 16) & 1u);
  return (u16)(u >> 16);
}

// XOR-swizzled LDS addressing (T2)
#define INP_ADDR(r, byte) (((r) << 8) + ((byte) ^ (((r) & 7) << 4)))   // 256 B/row
#define X_ADDR(r, byte)   (((r) << 9) + ((byte) ^ (((r) & 7) << 4)))   // 512 B/row

__device__ __forceinline__ void gload_lds16(const void* g, void* l) {
  __builtin_amdgcn_global_load_lds((const __attribute__((address_space(1))) u32*)g,
                                   (__attribute__((address_space(3))) u32*)l, 16, 0, 0);
}

// ---------------- prep: bf16 frag-ordered weights + per-pair fused bias ----------------
__global__ void prep_kernel(const float* __restrict__ W1, const float* __restrict__ b1,
                            const float* __restrict__ W2,
                            const float* __restrict__ Wm, const float* __restrict__ Wv,
                            u16* __restrict__ W1f, u16* __restrict__ W2f,
                            u16* __restrict__ Whf, float* __restrict__ b1p) {
  int tid = blockIdx.x * 256 + threadIdx.x;
  int NT = gridDim.x * 256;
  for (int i = tid; i < 32768; i += NT) {   // W1f: kf<4, nf<16
    int j = i & 7, lane = (i >> 3) & 63, f = i >> 9;
    int nf = f & 15, kf = f >> 4;
    int n = nf * 16 + (lane & 15);
    int k = kf * 32 + 8 * (lane >> 4) + j;
    W1f[i] = f2bf(W1[k * 256 + n]);
  }
  for (int i = tid; i < 65536; i += NT) {   // W2f: kf<8, nf<16
    int j = i & 7, lane = (i >> 3) & 63, f = i >> 9;
    int nf = f & 15, kf = f >> 4;
    int n = nf * 16 + (lane & 15);
    int k = kf * 32 + 8 * (lane >> 4) + j;
    W2f[i] = f2bf(W2[k * 256 + n]);
  }
  for (int i = tid; i < 32768; i += NT) {   // Whf = [Wm | Wv]: kf<8, nf<8
    int j = i & 7, lane = (i >> 3) & 63, f = i >> 9;
    int nf = f & 7, kf = f >> 3;
    int n = nf * 16 + (lane & 15);
    int k = kf * 32 + 8 * (lane >> 4) + j;
    Whf[i] = f2bf(n < 64 ? Wm[k * 64 + n] : Wv[k * 64 + (n - 64)]);
  }
  if (tid < 768) {                          // pairs (0,1),(0,2),(1,2) -> W1 rows {0,4},{0,5},{1,5}
    int p = tid >> 8, h = tid & 255;
    const int r1[3] = {0, 0, 1};
    const int r2[3] = {4, 5, 5};
    b1p[tid] = b1[h] + W1[r1[p] * 256 + h] + W1[r2[p] * 256 + h];
  }
}

// ---------------- K1: build inp, layer 1, emit x1 in A-fragment order ----------------
__global__ __launch_bounds__(256, 2) void l1_kernel(
    const float* __restrict__ init_s, const float* __restrict__ cur_s,
    const float* __restrict__ emb,
    const u16* __restrict__ W1f, const float* __restrict__ b1p,
    u16* __restrict__ x1f) {
  extern __shared__ char smem[];
  char* inp = smem;            // [64][128] bf16 swizzled (16 KB)
  char* ost = smem + 16384;    // [64][256] bf16 swizzled (32 KB)

  const int t = threadIdx.x;
  const int lane = t & 63;
  const int wave = t >> 6;
  const int ql = lane & 15, qw = lane >> 4;
  const int b0 = blockIdx.x * 64;

  // W1 slice in registers (16 frags = 64 VGPR), reused across all 3 pairs
  bf16x8 w1r[4][4];
#pragma unroll
  for (int kf = 0; kf < 4; ++kf)
#pragma unroll
    for (int ni = 0; ni < 4; ++ni)
      w1r[kf][ni] = *(const bf16x8*)(W1f + (size_t)((kf * 16 + wave * 4 + ni) * 64 + lane) * 8);

  if (t < 64) {  // zero one-hot-folded cols 0..5
    *(unsigned long long*)(inp + INP_ADDR(t, 0)) = 0ull;
    *(unsigned int*)(inp + INP_ADDR(t, 8)) = 0u;
  }
  for (int i = t; i < 64 * 29; i += 256) {  // embedding cols 12..127
    int r = i / 29;
    int c4 = i - r * 29;
    const float4 v = *(const float4*)(emb + (size_t)(b0 + r) * 116 + c4 * 4);
    unsigned long long pk = (unsigned long long)f2bf(v.x)
                          | ((unsigned long long)f2bf(v.y) << 16)
                          | ((unsigned long long)f2bf(v.z) << 32)
                          | ((unsigned long long)f2bf(v.w) << 48);
    *(unsigned long long*)(inp + INP_ADDR(r, 24 + 8 * c4)) = pk;
  }

  const int IDSa[3] = {0, 1, 2};
  const int IDSb[3] = {3, 5, 7};
  const int IDSc[3] = {4, 6, 8};

#pragma unroll 1
  for (int p = 0; p < 3; ++p) {
    if (t < 64) {  // s-feature cols 6..11
      const float* isr = init_s + (size_t)(b0 + t) * 9;
      const float* csr = cur_s + (size_t)(b0 + t) * 9;
      float a0 = isr[IDSa[p]], a1 = isr[IDSb[p]], a2 = isr[IDSc[p]];
      float c0 = csr[IDSa[p]], c1 = csr[IDSb[p]], c2 = csr[IDSc[p]];
      *(unsigned int*)(inp + INP_ADDR(t, 12)) = (unsigned)f2bf(a0) | ((unsigned)f2bf(a1) << 16);
      *(unsigned int*)(inp + INP_ADDR(t, 16)) = (unsigned)f2bf(a2) | ((unsigned)f2bf(c0) << 16);
      *(unsigned int*)(inp + INP_ADDR(t, 20)) = (unsigned)f2bf(c1) | ((unsigned)f2bf(c2) << 16);
    }
    __syncthreads();

    f32x4 acc[4][4];
#pragma unroll
    for (int ni = 0; ni < 4; ++ni) {
      float bvv = b1p[p * 256 + wave * 64 + ni * 16 + ql];
#pragma unroll
      for (int mi = 0; mi < 4; ++mi) acc[mi][ni] = (f32x4){bvv, bvv, bvv, bvv};
    }
#pragma unroll
    for (int kf = 0; kf < 4; ++kf) {
      bf16x8 a[4];
#pragma unroll
      for (int mi = 0; mi < 4; ++mi)
        a[mi] = *(const bf16x8*)(inp + INP_ADDR(mi * 16 + ql, kf * 64 + qw * 16));
#pragma unroll
      for (int ni = 0; ni < 4; ++ni)
#pragma unroll
        for (int mi = 0; mi < 4; ++mi)
          acc[mi][ni] = __builtin_amdgcn_mfma_f32_16x16x32_bf16(a[mi], w1r[kf][ni], acc[mi][ni], 0, 0, 0);
    }
#pragma unroll
    for (int mi = 0; mi < 4; ++mi)
#pragma unroll
      for (int ni = 0; ni < 4; ++ni) {
        int col = wave * 64 + ni * 16 + ql;
#pragma unroll
        for (int r = 0; r < 4; ++r) {
          int row = mi * 16 + qw * 4 + r;
          float v = acc[mi][ni][r];
          v = v > 0.f ? v : 0.f;
          *(u16*)(ost + X_ADDR(row, col * 2)) = f2bf(v);
        }
      }
    __syncthreads();

    // export 8 A-frags per wave -> x1f (frag order: tau*32 + kf3*4 + mi, 1 KB each)
    size_t tbase = ((size_t)(p * NT1 + blockIdx.x)) * 32768;
#pragma unroll
    for (int f = 0; f < 8; ++f) {
      int kf3 = wave * 2 + (f >> 2), mi = f & 3;
      bf16x8 v = *(const bf16x8*)(ost + X_ADDR(mi * 16 + ql, kf3 * 64 + qw * 16));
      *(bf16x8*)((char*)x1f + tbase + (size_t)(kf3 * 4 + mi) * 1024 + lane * 16) = v;
    }
  }
}

// ---------------- K2: layer 2, x1f -> x2f (in place), frag order in/out ----------------
__global__ __launch_bounds__(256, 2) void l2_kernel(
    const u16* __restrict__ x1f, const u16* __restrict__ W2f,
    const float* __restrict__ b2, u16* __restrict__ x2f) {
  extern __shared__ char smem[];
  char* At  = smem;            // staged A tile, frag-linear (32 KB)
  char* ost = smem + 32768;    // [64][256] bf16 swizzled (32 KB)

  const int t = threadIdx.x;
  const int lane = t & 63;
  const int wave = t >> 6;
  const int ql = lane & 15, qw = lane >> 4;

  bf16x8 w2r[8][4];            // 32 frags = 128 VGPR, loaded once
#pragma unroll
  for (int kf = 0; kf < 8; ++kf)
#pragma unroll
    for (int ni = 0; ni < 4; ++ni)
      w2r[kf][ni] = *(const bf16x8*)(W2f + (size_t)((kf * 16 + wave * 4 + ni) * 64 + lane) * 8);

  float bv0[4];
#pragma unroll
  for (int ni = 0; ni < 4; ++ni) bv0[ni] = b2[wave * 64 + ni * 16 + ql];

#pragma unroll 1
  for (int it = 0; it < 3; ++it) {
    int tau = blockIdx.x * 3 + it;
    const char* gbase = (const char*)x1f + (size_t)tau * 32768;
    {
      const char* gsrc = gbase + (size_t)(wave * 8) * 1024 + lane * 16;
      char* ldst = At + (wave * 8) * 1024;
#pragma unroll
      for (int i = 0; i < 8; ++i) gload_lds16(gsrc + i * 1024, ldst + i * 1024);
    }
    asm volatile("s_waitcnt vmcnt(0)" ::: "memory");
    __syncthreads();

    f32x4 acc[4][4];
#pragma unroll
    for (int ni = 0; ni < 4; ++ni)
#pragma unroll
      for (int mi = 0; mi < 4; ++mi) acc[mi][ni] = (f32x4){bv0[ni], bv0[ni], bv0[ni], bv0[ni]};
#pragma unroll
    for (int kf = 0; kf < 8; ++kf) {
      bf16x8 a[4];
#pragma unroll
      for (int mi = 0; mi < 4; ++mi)
        a[mi] = *(const bf16x8*)(At + (kf * 4 + mi) * 1024 + lane * 16);
#pragma unroll
      for (int ni = 0; ni < 4; ++ni)
#pragma unroll
        for (int mi = 0; mi < 4; ++mi)
          acc[mi][ni] = __builtin_amdgcn_mfma_f32_16x16x32_bf16(a[mi], w2r[kf][ni], acc[mi][ni], 0, 0, 0);
    }
#pragma unroll
    for (int mi = 0; mi < 4; ++mi)
#pragma unroll
      for (int ni = 0; ni < 4; ++ni) {
        int col = wave * 64 + ni * 16 + ql;
#pragma unroll
        for (int r = 0; r < 4; ++r) {
          int row = mi * 16 + qw * 4 + r;
          float v = acc[mi][ni][r];
          v = v > 0.f ? v : 0.f;
          *(u16*)(ost + X_ADDR(row, col * 2)) = f2bf(v);
        }
      }
    __syncthreads();

    size_t tbase = (size_t)tau * 32768;
#pragma unroll
    for (int f = 0; f < 8; ++f) {
      int kf3 = wave * 2 + (f >> 2), mi = f & 3;
      bf16x8 v = *(const bf16x8*)(ost + X_ADDR(mi * 16 + ql, kf3 * 64 + qw * 16));
      *(bf16x8*)((char*)x2f + tbase + (size_t)(kf3 * 4 + mi) * 1024 + lane * 16) = v;
    }
  }
}

// ---------------- K3: heads, x2f -> out (f32, means | log_vars) ----------------
__global__ __launch_bounds__(256, 2) void head_kernel(
    const u16* __restrict__ x2f, const u16* __restrict__ Whf,
    const float* __restrict__ bm, const float* __restrict__ bv,
    float* __restrict__ out) {
  extern __shared__ char smem[];
  char* At  = smem;            // staged A tile (32 KB)
  char* ostF = smem + 32768;   // [64][128] f32, swizzled (32 KB)

  const int t = threadIdx.x;
  const int lane = t & 63;
  const int wave = t >> 6;
  const int ql = lane & 15, qw = lane >> 4;

  bf16x8 whr[8][2];            // 16 frags = 64 VGPR
#pragma unroll
  for (int kf = 0; kf < 8; ++kf)
#pragma unroll
    for (int ni = 0; ni < 2; ++ni)
      whr[kf][ni] = *(const bf16x8*)(Whf + (size_t)((kf * 8 + wave * 2 + ni) * 64 + lane) * 8);

  float hb[2];
#pragma unroll
  for (int ni = 0; ni < 2; ++ni) {
    int col = wave * 32 + ni * 16 + ql;
    hb[ni] = (col < 64) ? bm[col] : bv[col - 64];
  }

#pragma unroll 1
  for (int it = 0; it < 3; ++it) {
    int tau = blockIdx.x * 3 + it;
    const char* gbase = (const char*)x2f + (size_t)tau * 32768;
    {
      const char* gsrc = gbase + (size_t)(wave * 8) * 1024 + lane * 16;
      char* ldst = At + (wave * 8) * 1024;
#pragma unroll
      for (int i = 0; i < 8; ++i) gload_lds16(gsrc + i * 1024, ldst + i * 1024);
    }
    asm volatile("s_waitcnt vmcnt(0)" ::: "memory");
    __syncthreads();

    f32x4 acc[4][2];
#pragma unroll
    for (int ni = 0; ni < 2; ++ni)
#pragma unroll
      for (int mi = 0; mi < 4; ++mi) acc[mi][ni] = (f32x4){hb[ni], hb[ni], hb[ni], hb[ni]};
#pragma unroll
    for (int kf = 0; kf < 8; ++kf) {
      bf16x8 a[4];
#pragma unroll
      for (int mi = 0; mi < 4; ++mi)
        a[mi] = *(const bf16x8*)(At + (kf * 4 + mi) * 1024 + lane * 16);
#pragma unroll
      for (int ni = 0; ni < 2; ++ni)
#pragma unroll
        for (int mi = 0; mi < 4; ++mi)
          acc[mi][ni] = __builtin_amdgcn_mfma_f32_16x16x32_bf16(a[mi], whr[kf][ni], acc[mi][ni], 0, 0, 0);
    }
#pragma unroll
    for (int mi = 0; mi < 4; ++mi)
#pragma unroll
      for (int ni = 0; ni < 2; ++ni) {
        int col = wave * 32 + ni * 16 + ql;
#pragma unroll
        for (int r = 0; r < 4; ++r) {
          int row = mi * 16 + qw * 4 + r;
          *(float*)(ostF + row * 512 + ((col * 4) ^ ((row & 7) << 4))) = acc[mi][ni][r];
        }
      }
    __syncthreads();

    int p = tau >> 11;
    int tt = tau & 2047;
    int rb = tt * 64;
    for (int i = t; i < 64 * 32; i += 256) {
      int r = i >> 5, c4 = i & 31;
      float4 v = *(const float4*)(ostF + r * 512 + ((c4 * 16) ^ ((r & 7) << 4)));
      size_t off;
      if (c4 < 16)
        off = ((size_t)p * NB + rb + r) * 64 + (size_t)c4 * 4;
      else
        off = (size_t)3 * NB * 64 + ((size_t)p * NB + rb + r) * 64 + (size_t)(c4 - 16) * 4;
      *(float4*)(out + off) = v;
    }
    __syncthreads();
  }
}

// ---------------- fallback: round-1 fused kernel (used only if ws too small) ----------------
__global__ __launch_bounds__(256, 2) void fused_kernel(
    const float* __restrict__ init_s, const float* __restrict__ cur_s,
    const float* __restrict__ emb,
    const u16* __restrict__ W1f, const u16* __restrict__ W2f,
    const u16* __restrict__ Whf,
    const float* __restrict__ b1p, const float* __restrict__ b2,
    const float* __restrict__ bm, const float* __restrict__ bv,
    float* __restrict__ out) {
  extern __shared__ char smem[];
  char* inp = smem;
  char* x1  = smem + 16384;
  char* x2  = smem + 49152;
  float* ostage = (float*)(smem + 16384);

  const int t = threadIdx.x;
  const int lane = t & 63;
  const int wave = t >> 6;
  const int ql = lane & 15, qw = lane >> 4;
  const int b0 = blockIdx.x * 64;

  if (t < 64) {
    *(unsigned long long*)(inp + INP_ADDR(t, 0)) = 0ull;
    *(unsigned int*)(inp + INP_ADDR(t, 8)) = 0u;
  }
  for (int i = t; i < 64 * 29; i += 256) {
    int r = i / 29;
    int c4 = i - r * 29;
    const float4 v = *(const float4*)(emb + (size_t)(b0 + r) * 116 + c4 * 4);
    unsigned long long pk = (unsigned long long)f2bf(v.x)
                          | ((unsigned long long)f2bf(v.y) << 16)
                          | ((unsigned long long)f2bf(v.z) << 32)
                          | ((unsigned long long)f2bf(v.w) << 48);
    *(unsigned long long*)(inp + INP_ADDR(r, 24 + 8 * c4)) = pk;
  }

  const int IDSa[3] = {0, 1, 2};
  const int IDSb[3] = {3, 5, 7};
  const int IDSc[3] = {4, 6, 8};

#pragma unroll 1
  for (int p = 0; p < 3; ++p) {
    if (t < 64) {
      const float* isr = init_s + (size_t)(b0 + t) * 9;
      const float* csr = cur_s + (size_t)(b0 + t) * 9;
      float a0 = isr[IDSa[p]], a1 = isr[IDSb[p]], a2 = isr[IDSc[p]];
      float c0 = csr[IDSa[p]], c1 = csr[IDSb[p]], c2 = csr[IDSc[p]];
      *(unsigned int*)(inp + INP_ADDR(t, 12)) = (unsigned)f2bf(a0) | ((unsigned)f2bf(a1) << 16);
      *(unsigned int*)(inp + INP_ADDR(t, 16)) = (unsigned)f2bf(a2) | ((unsigned)f2bf(c0) << 16);
      *(unsigned int*)(inp + INP_ADDR(t, 20)) = (unsigned)f2bf(c1) | ((unsigned)f2bf(c2) << 16);
    }
    __syncthreads();

    {
      f32x4 acc[4][4];
#pragma unroll
      for (int ni = 0; ni < 4; ++ni) {
        float bvv = b1p[p * 256 + wave * 64 + ni * 16 + ql];
#pragma unroll
        for (int mi = 0; mi < 4; ++mi) acc[mi][ni] = (f32x4){bvv, bvv, bvv, bvv};
      }
#pragma unroll
      for (int kf = 0; kf < 4; ++kf) {
        bf16x8 a[4];
#pragma unroll
        for (int mi = 0; mi < 4; ++mi)
          a[mi] = *(const bf16x8*)(inp + INP_ADDR(mi * 16 + ql, kf * 64 + qw * 16));
#pragma unroll
        for (int ni = 0; ni < 4; ++ni) {
          bf16x8 w = *(const bf16x8*)(W1f + (size_t)((kf * 16 + wave * 4 + ni) * 64 + lane) * 8);
#pragma unroll
          for (int mi = 0; mi < 4; ++mi)
            acc[mi][ni] = __builtin_amdgcn_mfma_f32_16x16x32_bf16(a[mi], w, acc[mi][ni], 0, 0, 0);
        }
      }
#pragma unroll
      for (int mi = 0; mi < 4; ++mi)
#pragma unroll
        for (int ni = 0; ni < 4; ++ni) {
          int col = wave * 64 + ni * 16 + ql;
#pragma unroll
          for (int r = 0; r < 4; ++r) {
            int row = mi * 16 + qw * 4 + r;
            float v = acc[mi][ni][r];
            v = v > 0.f ? v : 0.f;
            *(u16*)(x1 + X_ADDR(row, col * 2)) = f2bf(v);
          }
        }
    }
    __syncthreads();

    {
      f32x4 acc[4][4];
#pragma unroll
      for (int ni = 0; ni < 4; ++ni) {
        float bvv = b2[wave * 64 + ni * 16 + ql];
#pragma unroll
        for (int mi = 0; mi < 4; ++mi) acc[mi][ni] = (f32x4){bvv, bvv, bvv, bvv};
      }
#pragma unroll
      for (int kf = 0; kf < 8; ++kf) {
        bf16x8 a[4];
#pragma unroll
        for (int mi = 0; mi < 4; ++mi)
          a[mi] = *(const bf16x8*)(x1 + X_ADDR(mi * 16 + ql, kf * 64 + qw * 16));
#pragma unroll
        for (int ni = 0; ni < 4; ++ni) {
          bf16x8 w = *(const bf16x8*)(W2f + (size_t)((kf * 16 + wave * 4 + ni) * 64 + lane) * 8);
#pragma unroll
          for (int mi = 0; mi < 4; ++mi)
            acc[mi][ni] = __builtin_amdgcn_mfma_f32_16x16x32_bf16(a[mi], w, acc[mi][ni], 0, 0, 0);
        }
      }
#pragma unroll
      for (int mi = 0; mi < 4; ++mi)
#pragma unroll
        for (int ni = 0; ni < 4; ++ni) {
          int col = wave * 64 + ni * 16 + ql;
#pragma unroll
          for (int r = 0; r < 4; ++r) {
            int row = mi * 16 + qw * 4 + r;
            float v = acc[mi][ni][r];
            v = v > 0.f ? v : 0.f;
            *(u16*)(x2 + X_ADDR(row, col * 2)) = f2bf(v);
          }
        }
    }
    __syncthreads();

    {
      f32x4 hacc[4][2];
#pragma unroll
      for (int ni = 0; ni < 2; ++ni) {
        int col = wave * 32 + ni * 16 + ql;
        float hbv = (col < 64) ? bm[col] : bv[col - 64];
#pragma unroll
        for (int mi = 0; mi < 4; ++mi) hacc[mi][ni] = (f32x4){hbv, hbv, hbv, hbv};
      }
#pragma unroll
      for (int kf = 0; kf < 8; ++kf) {
        bf16x8 a[4];
#pragma unroll
        for (int mi = 0; mi < 4; ++mi)
          a[mi] = *(const bf16x8*)(x2 + X_ADDR(mi * 16 + ql, kf * 64 + qw * 16));
#pragma unroll
        for (int ni = 0; ni < 2; ++ni) {
          bf16x8 w = *(const bf16x8*)(Whf + (size_t)((kf * 8 + wave * 2 + ni) * 64 + lane) * 8);
#pragma unroll
          for (int mi = 0; mi < 4; ++mi)
            hacc[mi][ni] = __builtin_amdgcn_mfma_f32_16x16x32_bf16(a[mi], w, hacc[mi][ni], 0, 0, 0);
        }
      }
#pragma unroll
      for (int mi = 0; mi < 4; ++mi)
#pragma unroll
        for (int ni = 0; ni < 2; ++ni) {
          int col = wave * 32 + ni * 16 + ql;
#pragma unroll
          for (int r = 0; r < 4; ++r)
            ostage[(mi * 16 + qw * 4 + r) * 128 + col] = hacc[mi][ni][r];
        }
    }
    __syncthreads();

    for (int i = t; i < 64 * 32; i += 256) {
      int r = i >> 5, c4 = i & 31;
      float4 v = *(const float4*)(ostage + r * 128 + c4 * 4);
      size_t off;
      if (c4 < 16)
        off = ((size_t)p * NB + b0 + r) * 64 + (size_t)c4 * 4;
      else
        off = (size_t)3 * NB * 64 + ((size_t)p * NB + b0 + r) * 64 + (size_t)(c4 - 16) * 4;
      *(float4*)(out + off) = v;
    }
    __syncthreads();
  }
}

extern "C" void kernel_launch(void* const* d_in, const int* in_sizes, int n_in,
                              void* d_out, int out_size, void* d_ws, size_t ws_size,
                              hipStream_t stream) {
  (void)in_sizes; (void)n_in; (void)out_size;
  const float* init_s = (const float*)d_in[0];
  const float* cur_s  = (const float*)d_in[1];
  const float* emb    = (const float*)d_in[2];
  const float* W1 = (const float*)d_in[3];
  const float* b1 = (const float*)d_in[4];
  const float* W2 = (const float*)d_in[5];
  const float* b2 = (const float*)d_in[6];
  const float* Wm = (const float*)d_in[7];
  const float* bm = (const float*)d_in[8];
  const float* Wv = (const float*)d_in[9];
  const float* bv = (const float*)d_in[10];

  u16* W1f = (u16*)d_ws;
  u16* W2f = (u16*)((char*)d_ws + 65536);
  u16* Whf = (u16*)((char*)d_ws + 196608);
  float* b1p = (float*)((char*)d_ws + 262144);

  prep_kernel<<<128, 256, 0, stream>>>(W1, b1, W2, Wm, Wv, W1f, W2f, Whf, b1p);

  const size_t need = (size_t)(1 << 20) + (size_t)NTT * 32768;  // 1 MB + 201.3 MB
  if (ws_size >= need) {
    u16* x1f = (u16*)((char*)d_ws + (1 << 20));  // x2 overwrites x1 in place (per-tile safe)

    (void)hipFuncSetAttribute((const void*)l1_kernel,
                              hipFuncAttributeMaxDynamicSharedMemorySize, 49152);
    (void)hipFuncSetAttribute((const void*)l2_kernel,
                              hipFuncAttributeMaxDynamicSharedMemorySize, 65536);
    (void)hipFuncSetAttribute((const void*)head_kernel,
                              hipFuncAttributeMaxDynamicSharedMemorySize, 65536);

    l1_kernel<<<NT1, 256, 49152, stream>>>(init_s, cur_s, emb, W1f, b1p, x1f);
    l2_kernel<<<NTT / 3, 256, 65536, stream>>>(x1f, W2f, b2, x1f);
    head_kernel<<<NTT / 3, 256, 65536, stream>>>(x1f, Whf, bm, bv, (float*)d_out);
  } else {
    (void)hipFuncSetAttribute((const void*)fused_kernel,
                              hipFuncAttributeMaxDynamicSharedMemorySize, 81920);
    fused_kernel<<<NB / 64, 256, 81920, stream>>>(init_s, cur_s, emb, W1f, W2f, Whf,
                                                  b1p, b2, bm, bv, (float*)d_out);
  }
}

// Round 3
// 251.660 us; speedup vs baseline: 2.3117x; 1.3458x over previous
//
#include <hip/hip_runtime.h>

typedef __attribute__((ext_vector_type(8))) __bf16 bf16x8;
typedef __attribute__((ext_vector_type(4))) float f32x4;
typedef unsigned int u32;
typedef unsigned short u16;

#define NB 131072   // batch
#define TPB 8       // row-tiles per block (grid 256)

__device__ __forceinline__ u16 f2bf(float f) {
  unsigned int u = __builtin_bit_cast(unsigned int, f);
  u += 0x7fffu + ((u >> 16) & 1u);
  return (u16)(u >> 16);
}

// XOR-swizzled LDS addressing (T2)
#define INP_ADDR(r, byte) (((r) << 8) + ((byte) ^ (((r) & 7) << 4)))   // 256 B/row
#define X_ADDR(r, byte)   (((r) << 9) + ((byte) ^ (((r) & 7) << 4)))   // 512 B/row

// ---------------- prep: bf16 frag-ordered weights + per-pair fused bias ----------------
// ws layout: W1f @0 (64KB), W2f @65536 (128KB), Whf @196608 (64KB), b1p @262144 (3KB)
__global__ void prep_kernel(const float* __restrict__ W1, const float* __restrict__ b1,
                            const float* __restrict__ W2,
                            const float* __restrict__ Wm, const float* __restrict__ Wv,
                            u16* __restrict__ W1f, u16* __restrict__ W2f,
                            u16* __restrict__ Whf, float* __restrict__ b1p) {
  int tid = blockIdx.x * 256 + threadIdx.x;
  int NT = gridDim.x * 256;
  for (int i = tid; i < 32768; i += NT) {   // W1f: frag f = kf*16+nf
    int j = i & 7, lane = (i >> 3) & 63, f = i >> 9;
    int nf = f & 15, kf = f >> 4;
    int n = nf * 16 + (lane & 15);
    int k = kf * 32 + 8 * (lane >> 4) + j;
    W1f[i] = f2bf(W1[k * 256 + n]);
  }
  for (int i = tid; i < 65536; i += NT) {   // W2f: f = kf*16+nf
    int j = i & 7, lane = (i >> 3) & 63, f = i >> 9;
    int nf = f & 15, kf = f >> 4;
    int n = nf * 16 + (lane & 15);
    int k = kf * 32 + 8 * (lane >> 4) + j;
    W2f[i] = f2bf(W2[k * 256 + n]);
  }
  for (int i = tid; i < 32768; i += NT) {   // Whf = [Wm | Wv]: f = kf*8+nf
    int j = i & 7, lane = (i >> 3) & 63, f = i >> 9;
    int nf = f & 7, kf = f >> 3;
    int n = nf * 16 + (lane & 15);
    int k = kf * 32 + 8 * (lane >> 4) + j;
    Whf[i] = f2bf(n < 64 ? Wm[k * 64 + n] : Wv[k * 64 + (n - 64)]);
  }
  if (tid < 768) {                          // pairs (0,1),(0,2),(1,2) -> W1 rows {0,4},{0,5},{1,5}
    int p = tid >> 8, h = tid & 255;
    const int r1[3] = {0, 0, 1};
    const int r2[3] = {4, 5, 5};
    b1p[tid] = b1[h] + W1[r1[p] * 256 + h] + W1[r2[p] * 256 + h];
  }
}

// ---------------- fully fused encoder: 4 waves, N-split-4, weights in VGPRs ----------------
__global__ __launch_bounds__(256, 1) void fused_kernel(
    const float* __restrict__ init_s, const float* __restrict__ cur_s,
    const float* __restrict__ emb,
    const u16* __restrict__ W1f, const u16* __restrict__ W2f,
    const u16* __restrict__ Whf,
    const float* __restrict__ b1p, const float* __restrict__ b2,
    const float* __restrict__ bm, const float* __restrict__ bv,
    float* __restrict__ out) {
  extern __shared__ char smem[];
  char* inp = smem;            // [64][128] bf16 swizzled (16 KB)
  char* x1  = smem + 16384;    // [64][256] bf16 swizzled (32 KB); ostage aliases
  char* x2  = smem + 49152;    // [64][256] bf16 swizzled (32 KB)
  char* ost = x1;              // [64][128] f32 swizzled (32 KB)

  const int t = threadIdx.x;
  const int lane = t & 63;
  const int wave = t >> 6;     // 0..3, owns 64 cols of L1/L2, 32 cols of heads
  const int ql = lane & 15, qw = lane >> 4;

  // ---- all weights in registers (64 frags = 256 VGPR), loaded once per block ----
  bf16x8 w1r[4][4];
#pragma unroll
  for (int kf = 0; kf < 4; ++kf)
#pragma unroll
    for (int ni = 0; ni < 4; ++ni)
      w1r[kf][ni] = *(const bf16x8*)(W1f + (size_t)((kf * 16 + wave * 4 + ni) * 64 + lane) * 8);
  bf16x8 w2r[8][4];
#pragma unroll
  for (int kf = 0; kf < 8; ++kf)
#pragma unroll
    for (int ni = 0; ni < 4; ++ni)
      w2r[kf][ni] = *(const bf16x8*)(W2f + (size_t)((kf * 16 + wave * 4 + ni) * 64 + lane) * 8);
  bf16x8 whr[8][2];
#pragma unroll
  for (int kf = 0; kf < 8; ++kf)
#pragma unroll
    for (int ni = 0; ni < 2; ++ni)
      whr[kf][ni] = *(const bf16x8*)(Whf + (size_t)((kf * 8 + wave * 2 + ni) * 64 + lane) * 8);

  float b1v[3][4];
#pragma unroll
  for (int p = 0; p < 3; ++p)
#pragma unroll
    for (int ni = 0; ni < 4; ++ni)
      b1v[p][ni] = b1p[p * 256 + wave * 64 + ni * 16 + ql];
  float b2v[4];
#pragma unroll
  for (int ni = 0; ni < 4; ++ni) b2v[ni] = b2[wave * 64 + ni * 16 + ql];
  float hbv[2];
#pragma unroll
  for (int ni = 0; ni < 2; ++ni) {
    int col = wave * 32 + ni * 16 + ql;
    hbv[ni] = (col < 64) ? bm[col] : bv[col - 64];
  }

  if (t < 64) {  // one-hot-folded cols 0..5 are always zero
    *(unsigned long long*)(inp + INP_ADDR(t, 0)) = 0ull;
    *(unsigned int*)(inp + INP_ADDR(t, 8)) = 0u;
  }

  const int IDSa[3] = {0, 1, 2};
  const int IDSb[3] = {3, 5, 7};
  const int IDSc[3] = {4, 6, 8};

#pragma unroll 1
  for (int it = 0; it < TPB; ++it) {
    const int b0 = (blockIdx.x * TPB + it) * 64;
    __syncthreads();  // previous tile's readers of inp/x1 are done

    // embedding cols 12..127 for this tile
    for (int i = t; i < 64 * 29; i += 256) {
      int r = i / 29;
      int c4 = i - r * 29;
      const float4 v = *(const float4*)(emb + (size_t)(b0 + r) * 116 + c4 * 4);
      unsigned long long pk = (unsigned long long)f2bf(v.x)
                            | ((unsigned long long)f2bf(v.y) << 16)
                            | ((unsigned long long)f2bf(v.z) << 32)
                            | ((unsigned long long)f2bf(v.w) << 48);
      *(unsigned long long*)(inp + INP_ADDR(r, 24 + 8 * c4)) = pk;
    }

#pragma unroll 1
    for (int p = 0; p < 3; ++p) {
      if (t < 64) {  // s-feature cols 6..11
        const float* isr = init_s + (size_t)(b0 + t) * 9;
        const float* csr = cur_s + (size_t)(b0 + t) * 9;
        float a0 = isr[IDSa[p]], a1 = isr[IDSb[p]], a2 = isr[IDSc[p]];
        float c0 = csr[IDSa[p]], c1 = csr[IDSb[p]], c2 = csr[IDSc[p]];
        *(u32*)(inp + INP_ADDR(t, 12)) = (u32)f2bf(a0) | ((u32)f2bf(a1) << 16);
        *(u32*)(inp + INP_ADDR(t, 16)) = (u32)f2bf(a2) | ((u32)f2bf(c0) << 16);
        *(u32*)(inp + INP_ADDR(t, 20)) = (u32)f2bf(c1) | ((u32)f2bf(c2) << 16);
      }
      __syncthreads();

      // ---- layer 1: [64x128] @ W1 -> x1, wave cols [wave*64, +64) ----
      {
        f32x4 acc[4][4];
#pragma unroll
        for (int ni = 0; ni < 4; ++ni)
#pragma unroll
          for (int mi = 0; mi < 4; ++mi)
            acc[mi][ni] = (f32x4){b1v[p][ni], b1v[p][ni], b1v[p][ni], b1v[p][ni]};
#pragma unroll
        for (int kf = 0; kf < 4; ++kf) {
          bf16x8 a[4];
#pragma unroll
          for (int mi = 0; mi < 4; ++mi)
            a[mi] = *(const bf16x8*)(inp + INP_ADDR(mi * 16 + ql, kf * 64 + qw * 16));
#pragma unroll
          for (int ni = 0; ni < 4; ++ni)
#pragma unroll
            for (int mi = 0; mi < 4; ++mi)
              acc[mi][ni] = __builtin_amdgcn_mfma_f32_16x16x32_bf16(a[mi], w1r[kf][ni], acc[mi][ni], 0, 0, 0);
        }
#pragma unroll
        for (int mi = 0; mi < 4; ++mi)
#pragma unroll
          for (int ni = 0; ni < 4; ++ni) {
            int col = wave * 64 + ni * 16 + ql;
#pragma unroll
            for (int r = 0; r < 4; ++r) {
              int row = mi * 16 + qw * 4 + r;
              float v = acc[mi][ni][r];
              v = v > 0.f ? v : 0.f;
              *(u16*)(x1 + X_ADDR(row, col * 2)) = f2bf(v);
            }
          }
      }
      __syncthreads();

      // ---- layer 2: [64x256] @ W2 -> x2 ----
      {
        f32x4 acc[4][4];
#pragma unroll
        for (int ni = 0; ni < 4; ++ni)
#pragma unroll
          for (int mi = 0; mi < 4; ++mi)
            acc[mi][ni] = (f32x4){b2v[ni], b2v[ni], b2v[ni], b2v[ni]};
#pragma unroll
        for (int kf = 0; kf < 8; ++kf) {
          bf16x8 a[4];
#pragma unroll
          for (int mi = 0; mi < 4; ++mi)
            a[mi] = *(const bf16x8*)(x1 + X_ADDR(mi * 16 + ql, kf * 64 + qw * 16));
#pragma unroll
          for (int ni = 0; ni < 4; ++ni)
#pragma unroll
            for (int mi = 0; mi < 4; ++mi)
              acc[mi][ni] = __builtin_amdgcn_mfma_f32_16x16x32_bf16(a[mi], w2r[kf][ni], acc[mi][ni], 0, 0, 0);
        }
#pragma unroll
        for (int mi = 0; mi < 4; ++mi)
#pragma unroll
          for (int ni = 0; ni < 4; ++ni) {
            int col = wave * 64 + ni * 16 + ql;
#pragma unroll
            for (int r = 0; r < 4; ++r) {
              int row = mi * 16 + qw * 4 + r;
              float v = acc[mi][ni][r];
              v = v > 0.f ? v : 0.f;
              *(u16*)(x2 + X_ADDR(row, col * 2)) = f2bf(v);
            }
          }
      }
      __syncthreads();

      // ---- heads: [64x256] @ [Wm|Wv] -> ostage (f32), wave cols [wave*32, +32) ----
      {
        f32x4 hacc[4][2];
#pragma unroll
        for (int ni = 0; ni < 2; ++ni)
#pragma unroll
          for (int mi = 0; mi < 4; ++mi)
            hacc[mi][ni] = (f32x4){hbv[ni], hbv[ni], hbv[ni], hbv[ni]};
#pragma unroll
        for (int kf = 0; kf < 8; ++kf) {
          bf16x8 a[4];
#pragma unroll
          for (int mi = 0; mi < 4; ++mi)
            a[mi] = *(const bf16x8*)(x2 + X_ADDR(mi * 16 + ql, kf * 64 + qw * 16));
#pragma unroll
          for (int ni = 0; ni < 2; ++ni)
#pragma unroll
            for (int mi = 0; mi < 4; ++mi)
              hacc[mi][ni] = __builtin_amdgcn_mfma_f32_16x16x32_bf16(a[mi], whr[kf][ni], hacc[mi][ni], 0, 0, 0);
        }
#pragma unroll
        for (int mi = 0; mi < 4; ++mi)
#pragma unroll
          for (int ni = 0; ni < 2; ++ni) {
            int col = wave * 32 + ni * 16 + ql;
#pragma unroll
            for (int r = 0; r < 4; ++r) {
              int row = mi * 16 + qw * 4 + r;
              *(float*)(ost + row * 512 + ((col * 4) ^ ((row & 7) << 4))) = hacc[mi][ni][r];
            }
          }
      }
      __syncthreads();

      // ---- coalesced export: cols 0-63 -> means, 64-127 -> log_vars ----
      for (int i = t; i < 64 * 32; i += 256) {
        int r = i >> 5, c4 = i & 31;
        float4 v = *(const float4*)(ost + r * 512 + ((c4 * 16) ^ ((r & 7) << 4)));
        size_t off;
        if (c4 < 16)
          off = ((size_t)p * NB + b0 + r) * 64 + (size_t)c4 * 4;
        else
          off = (size_t)3 * NB * 64 + ((size_t)p * NB + b0 + r) * 64 + (size_t)(c4 - 16) * 4;
        *(float4*)(out + off) = v;
      }
      // pair-top / tile-top __syncthreads orders these ost reads vs next x1 writes
    }
  }
}

extern "C" void kernel_launch(void* const* d_in, const int* in_sizes, int n_in,
                              void* d_out, int out_size, void* d_ws, size_t ws_size,
                              hipStream_t stream) {
  (void)in_sizes; (void)n_in; (void)out_size; (void)ws_size;
  const float* init_s = (const float*)d_in[0];
  const float* cur_s  = (const float*)d_in[1];
  const float* emb    = (const float*)d_in[2];
  const float* W1 = (const float*)d_in[3];
  const float* b1 = (const float*)d_in[4];
  const float* W2 = (const float*)d_in[5];
  const float* b2 = (const float*)d_in[6];
  const float* Wm = (const float*)d_in[7];
  const float* bm = (const float*)d_in[8];
  const float* Wv = (const float*)d_in[9];
  const float* bv = (const float*)d_in[10];

  u16* W1f = (u16*)d_ws;
  u16* W2f = (u16*)((char*)d_ws + 65536);
  u16* Whf = (u16*)((char*)d_ws + 196608);
  float* b1p = (float*)((char*)d_ws + 262144);

  prep_kernel<<<128, 256, 0, stream>>>(W1, b1, W2, Wm, Wv, W1f, W2f, Whf, b1p);

  (void)hipFuncSetAttribute((const void*)fused_kernel,
                            hipFuncAttributeMaxDynamicSharedMemorySize, 81920);
  fused_kernel<<<NB / (64 * TPB), 256, 81920, stream>>>(init_s, cur_s, emb, W1f, W2f, Whf,
                                                        b1p, b2, bm, bv, (float*)d_out);
}

// Round 4
// 174.558 us; speedup vs baseline: 3.3327x; 1.4417x over previous
//
#include <hip/hip_runtime.h>

typedef __attribute__((ext_vector_type(8))) __bf16 bf16x8;
typedef __attribute__((ext_vector_type(4))) float f32x4;
typedef unsigned int u32;
typedef unsigned short u16;

#define NB 131072   // batch
#define TPB 8       // row-tiles per block (grid 256, persistent)

__device__ __forceinline__ u16 f2bf(float f) {
  unsigned int u = __builtin_bit_cast(unsigned int, f);
  u += 0x7fffu + ((u >> 16) & 1u);
  return (u16)(u >> 16);
}

// XOR-swizzled LDS addressing (T2)
#define INP_ADDR(r, byte) (((r) << 8) + ((byte) ^ (((r) & 7) << 4)))   // 256 B/row
#define X_ADDR(r, byte)   (((r) << 9) + ((byte) ^ (((r) & 7) << 4)))   // 512 B/row

// ---------------- prep: bf16 frag-ordered weights + per-pair fused bias ----------------
// ws layout: W1f @0 (64KB), W2f @65536 (128KB), Whf @196608 (64KB), b1p @262144 (3KB)
__global__ void prep_kernel(const float* __restrict__ W1, const float* __restrict__ b1,
                            const float* __restrict__ W2,
                            const float* __restrict__ Wm, const float* __restrict__ Wv,
                            u16* __restrict__ W1f, u16* __restrict__ W2f,
                            u16* __restrict__ Whf, float* __restrict__ b1p) {
  int tid = blockIdx.x * 256 + threadIdx.x;
  int NT = gridDim.x * 256;
  for (int i = tid; i < 32768; i += NT) {   // W1f: frag f = kf*16+nf
    int j = i & 7, lane = (i >> 3) & 63, f = i >> 9;
    int nf = f & 15, kf = f >> 4;
    int n = nf * 16 + (lane & 15);
    int k = kf * 32 + 8 * (lane >> 4) + j;
    W1f[i] = f2bf(W1[k * 256 + n]);
  }
  for (int i = tid; i < 65536; i += NT) {   // W2f: f = kf*16+nf
    int j = i & 7, lane = (i >> 3) & 63, f = i >> 9;
    int nf = f & 15, kf = f >> 4;
    int n = nf * 16 + (lane & 15);
    int k = kf * 32 + 8 * (lane >> 4) + j;
    W2f[i] = f2bf(W2[k * 256 + n]);
  }
  for (int i = tid; i < 32768; i += NT) {   // Whf = [Wm | Wv]: f = kf*8+nf
    int j = i & 7, lane = (i >> 3) & 63, f = i >> 9;
    int nf = f & 7, kf = f >> 3;
    int n = nf * 16 + (lane & 15);
    int k = kf * 32 + 8 * (lane >> 4) + j;
    Whf[i] = f2bf(n < 64 ? Wm[k * 64 + n] : Wv[k * 64 + (n - 64)]);
  }
  if (tid < 768) {                          // pairs (0,1),(0,2),(1,2) -> W1 rows {0,4},{0,5},{1,5}
    int p = tid >> 8, h = tid & 255;
    const int r1[3] = {0, 0, 1};
    const int r2[3] = {4, 5, 5};
    b1p[tid] = b1[h] + W1[r1[p] * 256 + h] + W1[r2[p] * 256 + h];
  }
}

// ---------------- fused encoder: 8 waves, N-split-8, weights in VGPRs, 2 waves/SIMD ----------------
__global__ __launch_bounds__(512, 2) void fused_kernel(
    const float* __restrict__ init_s, const float* __restrict__ cur_s,
    const float* __restrict__ emb,
    const u16* __restrict__ W1f, const u16* __restrict__ W2f,
    const u16* __restrict__ Whf,
    const float* __restrict__ b1p, const float* __restrict__ b2,
    const float* __restrict__ bm, const float* __restrict__ bv,
    float* __restrict__ out) {
  extern __shared__ char smem[];
  char* inp = smem;            // [64][128] bf16 swizzled (16 KB)
  char* x1  = smem + 16384;    // [64][256] bf16 swizzled (32 KB); ostage aliases
  char* x2  = smem + 49152;    // [64][256] bf16 swizzled (32 KB)
  char* ost = x1;              // [64][128] f32 swizzled (32 KB)
  float* sbI = (float*)(smem + 81920);          // [64][9] init_s tile (2304 B)
  float* sbC = (float*)(smem + 81920 + 2304);   // [64][9] cur_s tile  (2304 B)

  const int t = threadIdx.x;
  const int lane = t & 63;
  const int wave = t >> 6;     // 0..7: owns 32 cols of L1/L2, 16 head cols
  const int ql = lane & 15, qw = lane >> 4;

  // ---- weights in registers: 32 frags = 128 VGPR per wave, loaded once ----
  bf16x8 w1r[4][2];
#pragma unroll
  for (int kf = 0; kf < 4; ++kf)
#pragma unroll
    for (int ni = 0; ni < 2; ++ni)
      w1r[kf][ni] = *(const bf16x8*)(W1f + (size_t)((kf * 16 + wave * 2 + ni) * 64 + lane) * 8);
  bf16x8 w2r[8][2];
#pragma unroll
  for (int kf = 0; kf < 8; ++kf)
#pragma unroll
    for (int ni = 0; ni < 2; ++ni)
      w2r[kf][ni] = *(const bf16x8*)(W2f + (size_t)((kf * 16 + wave * 2 + ni) * 64 + lane) * 8);
  bf16x8 whr[8];
#pragma unroll
  for (int kf = 0; kf < 8; ++kf)
    whr[kf] = *(const bf16x8*)(Whf + (size_t)((kf * 8 + wave) * 64 + lane) * 8);

  float b1v[3][2];
#pragma unroll
  for (int p = 0; p < 3; ++p)
#pragma unroll
    for (int ni = 0; ni < 2; ++ni)
      b1v[p][ni] = b1p[p * 256 + wave * 32 + ni * 16 + ql];
  float b2v[2];
#pragma unroll
  for (int ni = 0; ni < 2; ++ni) b2v[ni] = b2[wave * 32 + ni * 16 + ql];
  const int hcol = wave * 16 + ql;
  const float hbv = (hcol < 64) ? bm[hcol] : bv[hcol - 64];

  if (t < 64) {  // one-hot-folded cols 0..5 are always zero
    *(unsigned long long*)(inp + INP_ADDR(t, 0)) = 0ull;
    *(u32*)(inp + INP_ADDR(t, 8)) = 0u;
  }

  const int IDSa[3] = {0, 1, 2};
  const int IDSb[3] = {3, 5, 7};
  const int IDSc[3] = {4, 6, 8};

#pragma unroll 1
  for (int it = 0; it < TPB; ++it) {
    const int b0 = (blockIdx.x * TPB + it) * 64;

    // ---- tile staging: embeddings -> inp cols 12..127; s tiles -> sbI/sbC ----
    for (int i = t; i < 64 * 29; i += 512) {
      int r = i / 29;
      int c4 = i - r * 29;
      const float4 v = *(const float4*)(emb + (size_t)(b0 + r) * 116 + c4 * 4);
      unsigned long long pk = (unsigned long long)f2bf(v.x)
                            | ((unsigned long long)f2bf(v.y) << 16)
                            | ((unsigned long long)f2bf(v.z) << 32)
                            | ((unsigned long long)f2bf(v.w) << 48);
      *(unsigned long long*)(inp + INP_ADDR(r, 24 + 8 * c4)) = pk;
    }
    if (t < 288) {  // 64 rows x 9 floats = 144 float4 each, fully coalesced
      int which = t >= 144;
      int idx = which ? t - 144 : t;
      const float* src = which ? cur_s : init_s;
      float* dst = which ? sbC : sbI;
      ((float4*)dst)[idx] = ((const float4*)(src + (size_t)b0 * 9))[idx];
    }

#pragma unroll 1
    for (int p = 0; p < 3; ++p) {
      if (p > 0) {
        // s-feature cols 6..11 from LDS-staged s tiles (no global latency)
        if (t < 64) {
          float a0 = sbI[t * 9 + IDSa[p]], a1 = sbI[t * 9 + IDSb[p]], a2 = sbI[t * 9 + IDSc[p]];
          float c0 = sbC[t * 9 + IDSa[p]], c1 = sbC[t * 9 + IDSb[p]], c2 = sbC[t * 9 + IDSc[p]];
          *(u32*)(inp + INP_ADDR(t, 12)) = (u32)f2bf(a0) | ((u32)f2bf(a1) << 16);
          *(u32*)(inp + INP_ADDR(t, 16)) = (u32)f2bf(a2) | ((u32)f2bf(c0) << 16);
          *(u32*)(inp + INP_ADDR(t, 20)) = (u32)f2bf(c1) | ((u32)f2bf(c2) << 16);
        }
      } else {
        __syncthreads();  // staging visible
        if (t < 64) {
          float a0 = sbI[t * 9 + 0], a1 = sbI[t * 9 + 3], a2 = sbI[t * 9 + 4];
          float c0 = sbC[t * 9 + 0], c1 = sbC[t * 9 + 3], c2 = sbC[t * 9 + 4];
          *(u32*)(inp + INP_ADDR(t, 12)) = (u32)f2bf(a0) | ((u32)f2bf(a1) << 16);
          *(u32*)(inp + INP_ADDR(t, 16)) = (u32)f2bf(a2) | ((u32)f2bf(c0) << 16);
          *(u32*)(inp + INP_ADDR(t, 20)) = (u32)f2bf(c1) | ((u32)f2bf(c2) << 16);
        }
      }
      __syncthreads();

      // ---- layer 1: [64x128] @ W1 -> x1, wave cols [wave*32, +32) ----
      {
        f32x4 acc[4][2];
#pragma unroll
        for (int ni = 0; ni < 2; ++ni)
#pragma unroll
          for (int mi = 0; mi < 4; ++mi)
            acc[mi][ni] = (f32x4){b1v[p][ni], b1v[p][ni], b1v[p][ni], b1v[p][ni]};
#pragma unroll
        for (int kf = 0; kf < 4; ++kf) {
          bf16x8 a[4];
#pragma unroll
          for (int mi = 0; mi < 4; ++mi)
            a[mi] = *(const bf16x8*)(inp + INP_ADDR(mi * 16 + ql, kf * 64 + qw * 16));
#pragma unroll
          for (int ni = 0; ni < 2; ++ni)
#pragma unroll
            for (int mi = 0; mi < 4; ++mi)
              acc[mi][ni] = __builtin_amdgcn_mfma_f32_16x16x32_bf16(a[mi], w1r[kf][ni], acc[mi][ni], 0, 0, 0);
        }
#pragma unroll
        for (int mi = 0; mi < 4; ++mi)
#pragma unroll
          for (int ni = 0; ni < 2; ++ni) {
            int col = wave * 32 + ni * 16 + ql;
#pragma unroll
            for (int r = 0; r < 4; ++r) {
              int row = mi * 16 + qw * 4 + r;
              float v = acc[mi][ni][r];
              v = v > 0.f ? v : 0.f;
              *(u16*)(x1 + X_ADDR(row, col * 2)) = f2bf(v);
            }
          }
      }
      __syncthreads();

      // ---- layer 2: [64x256] @ W2 -> x2 ----
      {
        f32x4 acc[4][2];
#pragma unroll
        for (int ni = 0; ni < 2; ++ni)
#pragma unroll
          for (int mi = 0; mi < 4; ++mi)
            acc[mi][ni] = (f32x4){b2v[ni], b2v[ni], b2v[ni], b2v[ni]};
#pragma unroll
        for (int kf = 0; kf < 8; ++kf) {
          bf16x8 a[4];
#pragma unroll
          for (int mi = 0; mi < 4; ++mi)
            a[mi] = *(const bf16x8*)(x1 + X_ADDR(mi * 16 + ql, kf * 64 + qw * 16));
#pragma unroll
          for (int ni = 0; ni < 2; ++ni)
#pragma unroll
            for (int mi = 0; mi < 4; ++mi)
              acc[mi][ni] = __builtin_amdgcn_mfma_f32_16x16x32_bf16(a[mi], w2r[kf][ni], acc[mi][ni], 0, 0, 0);
        }
#pragma unroll
        for (int mi = 0; mi < 4; ++mi)
#pragma unroll
          for (int ni = 0; ni < 2; ++ni) {
            int col = wave * 32 + ni * 16 + ql;
#pragma unroll
            for (int r = 0; r < 4; ++r) {
              int row = mi * 16 + qw * 4 + r;
              float v = acc[mi][ni][r];
              v = v > 0.f ? v : 0.f;
              *(u16*)(x2 + X_ADDR(row, col * 2)) = f2bf(v);
            }
          }
      }
      __syncthreads();

      // ---- heads: [64x256] @ [Wm|Wv] -> ost (f32), wave col block [wave*16, +16) ----
      {
        f32x4 hacc[4];
#pragma unroll
        for (int mi = 0; mi < 4; ++mi)
          hacc[mi] = (f32x4){hbv, hbv, hbv, hbv};
#pragma unroll
        for (int kf = 0; kf < 8; ++kf) {
          bf16x8 a[4];
#pragma unroll
          for (int mi = 0; mi < 4; ++mi)
            a[mi] = *(const bf16x8*)(x2 + X_ADDR(mi * 16 + ql, kf * 64 + qw * 16));
#pragma unroll
          for (int mi = 0; mi < 4; ++mi)
            hacc[mi] = __builtin_amdgcn_mfma_f32_16x16x32_bf16(a[mi], whr[kf], hacc[mi], 0, 0, 0);
        }
#pragma unroll
        for (int mi = 0; mi < 4; ++mi) {
#pragma unroll
          for (int r = 0; r < 4; ++r) {
            int row = mi * 16 + qw * 4 + r;
            *(float*)(ost + row * 512 + ((hcol * 4) ^ ((row & 7) << 4))) = hacc[mi][r];
          }
        }
      }
      __syncthreads();

      // ---- coalesced export: cols 0-63 -> means, 64-127 -> log_vars ----
      for (int i = t; i < 64 * 32; i += 512) {
        int r = i >> 5, c4 = i & 31;
        float4 v = *(const float4*)(ost + r * 512 + ((c4 * 16) ^ ((r & 7) << 4)));
        size_t off;
        if (c4 < 16)
          off = ((size_t)p * NB + b0 + r) * 64 + (size_t)c4 * 4;
        else
          off = (size_t)3 * NB * 64 + ((size_t)p * NB + b0 + r) * 64 + (size_t)(c4 - 16) * 4;
        *(float4*)(out + off) = v;
      }
      // next iteration's s-feat barrier orders ost reads vs next x1 writes
    }
  }
}

extern "C" void kernel_launch(void* const* d_in, const int* in_sizes, int n_in,
                              void* d_out, int out_size, void* d_ws, size_t ws_size,
                              hipStream_t stream) {
  (void)in_sizes; (void)n_in; (void)out_size; (void)ws_size;
  const float* init_s = (const float*)d_in[0];
  const float* cur_s  = (const float*)d_in[1];
  const float* emb    = (const float*)d_in[2];
  const float* W1 = (const float*)d_in[3];
  const float* b1 = (const float*)d_in[4];
  const float* W2 = (const float*)d_in[5];
  const float* b2 = (const float*)d_in[6];
  const float* Wm = (const float*)d_in[7];
  const float* bm = (const float*)d_in[8];
  const float* Wv = (const float*)d_in[9];
  const float* bv = (const float*)d_in[10];

  u16* W1f = (u16*)d_ws;
  u16* W2f = (u16*)((char*)d_ws + 65536);
  u16* Whf = (u16*)((char*)d_ws + 196608);
  float* b1p = (float*)((char*)d_ws + 262144);

  prep_kernel<<<128, 256, 0, stream>>>(W1, b1, W2, Wm, Wv, W1f, W2f, Whf, b1p);

  const int lds_bytes = 16384 + 32768 + 32768 + 4608;  // 86528
  (void)hipFuncSetAttribute((const void*)fused_kernel,
                            hipFuncAttributeMaxDynamicSharedMemorySize, lds_bytes);
  fused_kernel<<<NB / (64 * TPB), 512, lds_bytes, stream>>>(init_s, cur_s, emb, W1f, W2f, Whf,
                                                            b1p, b2, bm, bv, (float*)d_out);
}

// Round 5
// 149.815 us; speedup vs baseline: 3.8832x; 1.1652x over previous
//
#include <hip/hip_runtime.h>

typedef __attribute__((ext_vector_type(8))) __bf16 bf16x8;
typedef __attribute__((ext_vector_type(4))) float f32x4;
typedef unsigned int u32;
typedef unsigned long long u64;
typedef unsigned short u16;

#define NB 131072   // batch
#define TPB 8       // row-tiles per block (grid 256, persistent)

__device__ __forceinline__ u16 f2bf(float f) {
  unsigned int u = __builtin_bit_cast(unsigned int, f);
  u += 0x7fffu + ((u >> 16) & 1u);
  return (u16)(u >> 16);
}

// XOR-swizzled LDS addressing (T2)
#define INP_ADDR(r, byte) (((r) << 8) + ((byte) ^ (((r) & 7) << 4)))   // 256 B/row
#define X_ADDR(r, byte)   (((r) << 9) + ((byte) ^ (((r) & 7) << 4)))   // 512 B/row

// ---------------- prep: bf16 frag-ordered weights + per-pair fused bias ----------------
// ws layout: W1f @0 (64KB), W2f @65536 (128KB), Whf @196608 (64KB), b1p @262144 (3KB)
__global__ void prep_kernel(const float* __restrict__ W1, const float* __restrict__ b1,
                            const float* __restrict__ W2,
                            const float* __restrict__ Wm, const float* __restrict__ Wv,
                            u16* __restrict__ W1f, u16* __restrict__ W2f,
                            u16* __restrict__ Whf, float* __restrict__ b1p) {
  int tid = blockIdx.x * 256 + threadIdx.x;
  int NT = gridDim.x * 256;
  for (int i = tid; i < 32768; i += NT) {   // W1f: frag f = kf*16+nf
    int j = i & 7, lane = (i >> 3) & 63, f = i >> 9;
    int nf = f & 15, kf = f >> 4;
    int n = nf * 16 + (lane & 15);
    int k = kf * 32 + 8 * (lane >> 4) + j;
    W1f[i] = f2bf(W1[k * 256 + n]);
  }
  for (int i = tid; i < 65536; i += NT) {   // W2f: f = kf*16+nf
    int j = i & 7, lane = (i >> 3) & 63, f = i >> 9;
    int nf = f & 15, kf = f >> 4;
    int n = nf * 16 + (lane & 15);
    int k = kf * 32 + 8 * (lane >> 4) + j;
    W2f[i] = f2bf(W2[k * 256 + n]);
  }
  for (int i = tid; i < 32768; i += NT) {   // Whf = [Wm | Wv]: f = kf*8+nf
    int j = i & 7, lane = (i >> 3) & 63, f = i >> 9;
    int nf = f & 7, kf = f >> 3;
    int n = nf * 16 + (lane & 15);
    int k = kf * 32 + 8 * (lane >> 4) + j;
    Whf[i] = f2bf(n < 64 ? Wm[k * 64 + n] : Wv[k * 64 + (n - 64)]);
  }
  if (tid < 768) {                          // pairs (0,1),(0,2),(1,2) -> W1 rows {0,4},{0,5},{1,5}
    int p = tid >> 8, h = tid & 255;
    const int r1[3] = {0, 0, 1};
    const int r2[3] = {4, 5, 5};
    b1p[tid] = b1[h] + W1[r1[p] * 256 + h] + W1[r2[p] * 256 + h];
  }
}

// ---------- fused encoder: 8 waves, operand-swapped MFMA (D = W^T X^T), 2 waves/SIMD ----------
__global__ __launch_bounds__(512, 2) void fused_kernel(
    const float* __restrict__ init_s, const float* __restrict__ cur_s,
    const float* __restrict__ emb,
    const u16* __restrict__ W1f, const u16* __restrict__ W2f,
    const u16* __restrict__ Whf,
    const float* __restrict__ b1p, const float* __restrict__ b2,
    const float* __restrict__ bm, const float* __restrict__ bv,
    float* __restrict__ out) {
  extern __shared__ char smem[];
  char* inp = smem;            // [64][128] bf16 swizzled (16 KB)
  char* x1  = smem + 16384;    // [64][256] bf16 swizzled (32 KB); ost aliases
  char* x2  = smem + 49152;    // [64][256] bf16 swizzled (32 KB)
  char* ost = x1;              // [64 batch][128 hcol] f32 swizzled (32 KB)
  float* sbI = (float*)(smem + 81920);          // [64][9] init_s tile
  float* sbC = (float*)(smem + 81920 + 2304);   // [64][9] cur_s tile

  const int t = threadIdx.x;
  const int lane = t & 63;
  const int wave = t >> 6;     // 0..7: owns 32 n-cols of L1/L2, 16 head cols
  const int ql = lane & 15, qw = lane >> 4;

  // ---- weights in registers (A-operand after swap): 32 frags = 128 regs/wave ----
  bf16x8 w1r[4][2];
#pragma unroll
  for (int kf = 0; kf < 4; ++kf)
#pragma unroll
    for (int ni = 0; ni < 2; ++ni)
      w1r[kf][ni] = *(const bf16x8*)(W1f + (size_t)((kf * 16 + wave * 2 + ni) * 64 + lane) * 8);
  bf16x8 w2r[8][2];
#pragma unroll
  for (int kf = 0; kf < 8; ++kf)
#pragma unroll
    for (int ni = 0; ni < 2; ++ni)
      w2r[kf][ni] = *(const bf16x8*)(W2f + (size_t)((kf * 16 + wave * 2 + ni) * 64 + lane) * 8);
  bf16x8 whr[8];
#pragma unroll
  for (int kf = 0; kf < 8; ++kf)
    whr[kf] = *(const bf16x8*)(Whf + (size_t)((kf * 8 + wave) * 64 + lane) * 8);

  // head bias: n = wave*16 + qw*4 + r (4 consecutive, never straddles 64)
  const int hn = wave * 16 + qw * 4;
  const f32x4 hbv = (hn < 64) ? *(const f32x4*)(bm + hn) : *(const f32x4*)(bv + hn - 64);

  if (t < 64) {  // one-hot-folded cols 0..5 are always zero
    *(u64*)(inp + INP_ADDR(t, 0)) = 0ull;
    *(u32*)(inp + INP_ADDR(t, 8)) = 0u;
  }

  const int IDSa[3] = {0, 1, 2};
  const int IDSb[3] = {3, 5, 7};
  const int IDSc[3] = {4, 6, 8};

#pragma unroll 1
  for (int it = 0; it < TPB; ++it) {
    const int b0 = (blockIdx.x * TPB + it) * 64;

    // ---- tile staging: embeddings -> inp cols 12..127; s tiles -> sbI/sbC ----
    for (int i = t; i < 64 * 29; i += 512) {
      int r = i / 29;
      int c4 = i - r * 29;
      const float4 v = *(const float4*)(emb + (size_t)(b0 + r) * 116 + c4 * 4);
      u64 pk = (u64)f2bf(v.x) | ((u64)f2bf(v.y) << 16)
             | ((u64)f2bf(v.z) << 32) | ((u64)f2bf(v.w) << 48);
      *(u64*)(inp + INP_ADDR(r, 24 + 8 * c4)) = pk;
    }
    if (t < 288) {  // 64 rows x 9 floats = 144 float4 each, fully coalesced
      int which = t >= 144;
      int idx = which ? t - 144 : t;
      const float* src = which ? cur_s : init_s;
      float* dst = which ? sbC : sbI;
      ((float4*)dst)[idx] = ((const float4*)(src + (size_t)b0 * 9))[idx];
    }

#pragma unroll 1
    for (int p = 0; p < 3; ++p) {
      if (p == 0) __syncthreads();  // staging visible
      if (t < 64) {  // s-feature cols 6..11 from LDS-staged s tiles
        float a0 = sbI[t * 9 + IDSa[p]], a1 = sbI[t * 9 + IDSb[p]], a2 = sbI[t * 9 + IDSc[p]];
        float c0 = sbC[t * 9 + IDSa[p]], c1 = sbC[t * 9 + IDSb[p]], c2 = sbC[t * 9 + IDSc[p]];
        *(u32*)(inp + INP_ADDR(t, 12)) = (u32)f2bf(a0) | ((u32)f2bf(a1) << 16);
        *(u32*)(inp + INP_ADDR(t, 16)) = (u32)f2bf(a2) | ((u32)f2bf(c0) << 16);
        *(u32*)(inp + INP_ADDR(t, 20)) = (u32)f2bf(c1) | ((u32)f2bf(c2) << 16);
      }
      __syncthreads();

      // ---- layer 1: D = W1^T X^T; wave owns n cols [wave*32, +32) ----
      {
        f32x4 acc[4][2];   // [batch-frag][n-frag]; reg r = n = base + qw*4 + r
#pragma unroll
        for (int ni = 0; ni < 2; ++ni) {
          f32x4 bb = *(const f32x4*)(b1p + p * 256 + wave * 32 + ni * 16 + qw * 4);
#pragma unroll
          for (int bf = 0; bf < 4; ++bf) acc[bf][ni] = bb;
        }
#pragma unroll
        for (int kf = 0; kf < 4; ++kf) {
          bf16x8 b[4];
#pragma unroll
          for (int bf = 0; bf < 4; ++bf)
            b[bf] = *(const bf16x8*)(inp + INP_ADDR(bf * 16 + ql, kf * 64 + qw * 16));
#pragma unroll
          for (int ni = 0; ni < 2; ++ni)
#pragma unroll
            for (int bf = 0; bf < 4; ++bf)
              acc[bf][ni] = __builtin_amdgcn_mfma_f32_16x16x32_bf16(w1r[kf][ni], b[bf], acc[bf][ni], 0, 0, 0);
        }
        // writeback: thread holds 4 consecutive n at fixed batch -> one b64 per frag
#pragma unroll
        for (int bf = 0; bf < 4; ++bf)
#pragma unroll
          for (int ni = 0; ni < 2; ++ni) {
            int row = bf * 16 + ql;                       // batch
            int byte = wave * 64 + ni * 32 + qw * 8;      // n*2
            f32x4 v = acc[bf][ni];
            float v0 = v[0] > 0.f ? v[0] : 0.f, v1 = v[1] > 0.f ? v[1] : 0.f;
            float v2 = v[2] > 0.f ? v[2] : 0.f, v3 = v[3] > 0.f ? v[3] : 0.f;
            u64 pk = (u64)f2bf(v0) | ((u64)f2bf(v1) << 16)
                   | ((u64)f2bf(v2) << 32) | ((u64)f2bf(v3) << 48);
            *(u64*)(x1 + X_ADDR(row, byte)) = pk;
          }
      }
      __syncthreads();

      // ---- layer 2: x1 -> x2 ----
      {
        f32x4 acc[4][2];
#pragma unroll
        for (int ni = 0; ni < 2; ++ni) {
          f32x4 bb = *(const f32x4*)(b2 + wave * 32 + ni * 16 + qw * 4);
#pragma unroll
          for (int bf = 0; bf < 4; ++bf) acc[bf][ni] = bb;
        }
#pragma unroll
        for (int kf = 0; kf < 8; ++kf) {
          bf16x8 b[4];
#pragma unroll
          for (int bf = 0; bf < 4; ++bf)
            b[bf] = *(const bf16x8*)(x1 + X_ADDR(bf * 16 + ql, kf * 64 + qw * 16));
#pragma unroll
          for (int ni = 0; ni < 2; ++ni)
#pragma unroll
            for (int bf = 0; bf < 4; ++bf)
              acc[bf][ni] = __builtin_amdgcn_mfma_f32_16x16x32_bf16(w2r[kf][ni], b[bf], acc[bf][ni], 0, 0, 0);
        }
#pragma unroll
        for (int bf = 0; bf < 4; ++bf)
#pragma unroll
          for (int ni = 0; ni < 2; ++ni) {
            int row = bf * 16 + ql;
            int byte = wave * 64 + ni * 32 + qw * 8;
            f32x4 v = acc[bf][ni];
            float v0 = v[0] > 0.f ? v[0] : 0.f, v1 = v[1] > 0.f ? v[1] : 0.f;
            float v2 = v[2] > 0.f ? v[2] : 0.f, v3 = v[3] > 0.f ? v[3] : 0.f;
            u64 pk = (u64)f2bf(v0) | ((u64)f2bf(v1) << 16)
                   | ((u64)f2bf(v2) << 32) | ((u64)f2bf(v3) << 48);
            *(u64*)(x2 + X_ADDR(row, byte)) = pk;
          }
      }
      __syncthreads();

      // ---- heads: x2 @ [Wm|Wv]; wave owns head cols [wave*16, +16) ----
      {
        f32x4 hacc[4];
#pragma unroll
        for (int bf = 0; bf < 4; ++bf) hacc[bf] = hbv;
#pragma unroll
        for (int kf = 0; kf < 8; ++kf) {
          bf16x8 b[4];
#pragma unroll
          for (int bf = 0; bf < 4; ++bf)
            b[bf] = *(const bf16x8*)(x2 + X_ADDR(bf * 16 + ql, kf * 64 + qw * 16));
#pragma unroll
          for (int bf = 0; bf < 4; ++bf)
            hacc[bf] = __builtin_amdgcn_mfma_f32_16x16x32_bf16(whr[kf], b[bf], hacc[bf], 0, 0, 0);
        }
        // thread holds 4 consecutive head cols (f32) at fixed batch -> one b128
#pragma unroll
        for (int bf = 0; bf < 4; ++bf) {
          int row = bf * 16 + ql;                         // batch
          int byte = wave * 64 + qw * 16;                 // hcol*4
          *(f32x4*)(ost + row * 512 + (byte ^ ((row & 7) << 4))) = hacc[bf];
        }
      }
      __syncthreads();

      // ---- coalesced export: cols 0-63 -> means, 64-127 -> log_vars ----
      for (int i = t; i < 64 * 32; i += 512) {
        int r = i >> 5, c4 = i & 31;
        float4 v = *(const float4*)(ost + r * 512 + ((c4 * 16) ^ ((r & 7) << 4)));
        size_t off;
        if (c4 < 16)
          off = ((size_t)p * NB + b0 + r) * 64 + (size_t)c4 * 4;
        else
          off = (size_t)3 * NB * 64 + ((size_t)p * NB + b0 + r) * 64 + (size_t)(c4 - 16) * 4;
        *(float4*)(out + off) = v;
      }
      // next iteration's post-s-feat barrier orders ost reads vs next x1 writes
    }
  }
}

extern "C" void kernel_launch(void* const* d_in, const int* in_sizes, int n_in,
                              void* d_out, int out_size, void* d_ws, size_t ws_size,
                              hipStream_t stream) {
  (void)in_sizes; (void)n_in; (void)out_size; (void)ws_size;
  const float* init_s = (const float*)d_in[0];
  const float* cur_s  = (const float*)d_in[1];
  const float* emb    = (const float*)d_in[2];
  const float* W1 = (const float*)d_in[3];
  const float* b1 = (const float*)d_in[4];
  const float* W2 = (const float*)d_in[5];
  const float* b2 = (const float*)d_in[6];
  const float* Wm = (const float*)d_in[7];
  const float* bm = (const float*)d_in[8];
  const float* Wv = (const float*)d_in[9];
  const float* bv = (const float*)d_in[10];

  u16* W1f = (u16*)d_ws;
  u16* W2f = (u16*)((char*)d_ws + 65536);
  u16* Whf = (u16*)((char*)d_ws + 196608);
  float* b1p = (float*)((char*)d_ws + 262144);

  prep_kernel<<<128, 256, 0, stream>>>(W1, b1, W2, Wm, Wv, W1f, W2f, Whf, b1p);

  const int lds_bytes = 16384 + 32768 + 32768 + 4608;  // 86528
  (void)hipFuncSetAttribute((const void*)fused_kernel,
                            hipFuncAttributeMaxDynamicSharedMemorySize, lds_bytes);
  fused_kernel<<<NB / (64 * TPB), 512, lds_bytes, stream>>>(init_s, cur_s, emb, W1f, W2f, Whf,
                                                            b1p, b2, bm, bv, (float*)d_out);
}